// Round 2
// baseline (148.243 us; speedup 1.0000x reference)
//
#include <hip/hip_runtime.h>
#include <hip/hip_bf16.h>
#include <stdint.h>

#define VOCAB 100000
#define SEQ   8192
#define BATCH 8
#define DIM   128
#define NB_WLT 1563   // (VOCAB+63)/64

typedef short bf16x8 __attribute__((ext_vector_type(8)));
typedef float f32x4  __attribute__((ext_vector_type(4)));

__device__ __forceinline__ ushort f2bf(float f) {
  union { float f; uint32_t u; } v; v.f = f;
  uint32_t u = v.u;
  return (ushort)((u + 0x7FFF + ((u >> 16) & 1)) >> 16);  // RNE; inputs never NaN
}

// ---------------------------------------------------------------------------
// Fused pre-kernel: blocks [0, NB_WLT) build wlt (LDS tile transpose of W_lin
// + bias -> bf16, token-major); blocks [NB_WLT, NB_WLT+80) repack W_conv
// (d,i,k) fp32 -> wcb[k][d][i] bf16 (160 KB, L2-hot B operand).
// ---------------------------------------------------------------------------
__global__ __launch_bounds__(256) void build_tables(
    const float* __restrict__ wlin, const float* __restrict__ blin,
    const float* __restrict__ wconv, ushort* __restrict__ wlt,
    ushort* __restrict__ wcb) {
  __shared__ float tile[128 * 65];
  const int tid = threadIdx.x;

  if (blockIdx.x >= NB_WLT) {
    int e = (blockIdx.x - NB_WLT) * 1024 + tid;
#pragma unroll
    for (int i = 0; i < 4; ++i, e += 256) {
      if (e < 5 * DIM * DIM) {
        int k = e >> 14;            // / (DIM*DIM)
        int rem = e & 16383;        // % (DIM*DIM)
        int d = rem >> 7, ii = rem & 127;
        wcb[e] = f2bf(wconv[(d * DIM + ii) * 5 + k]);
      }
    }
    return;
  }

  const int t0 = blockIdx.x * 64;

  // Phase A: 8 passes, each covers 16 rows x 64 cols in float4s.
  const int c4 = (tid & 15) * 4;          // column offset within tile (0..60)
  const int rbase = tid >> 4;             // 0..15
  const bool cvalid = (t0 + c4) < VOCAB;  // VOCAB%4==0 -> whole float4 in/out
#pragma unroll
  for (int p = 0; p < 8; ++p) {
    int r = p * 16 + rbase;               // dim row 0..127
    float4 v = make_float4(0.f, 0.f, 0.f, 0.f);
    if (cvalid) v = *(const float4*)(wlin + (size_t)r * VOCAB + t0 + c4);
    float* dst = &tile[r * 65 + c4];
    dst[0] = v.x; dst[1] = v.y; dst[2] = v.z; dst[3] = v.w;
  }
  __syncthreads();

  // Phase B: thread = (chunk = tid&15, token = tid>>4 + p*16)
  const int chunk = tid & 15;
  float bias8[8];
#pragma unroll
  for (int j = 0; j < 8; ++j) bias8[j] = blin[chunk * 8 + j];

#pragma unroll
  for (int p = 0; p < 4; ++p) {
    int tl = (tid >> 4) + p * 16;         // token within tile 0..63
    int t  = t0 + tl;
    if (t >= VOCAB) continue;
    ushort u[8];
#pragma unroll
    for (int j = 0; j < 8; ++j) {
      float f = tile[(chunk * 8 + j) * 65 + tl] + bias8[j];
      u[j] = f2bf(f);
    }
    *(uint4*)(wlt + (size_t)t * DIM + chunk * 8) = *(const uint4*)u;
  }
}

// ---------------------------------------------------------------------------
// Main: per block: 128 positions x 128 out-channels.
// LDS A-tile: 132 emb rows (halo +-2) x 128 bf16, pitch 136 ushorts (272 B)
//   -> ds_read_b128 bank pattern (17r+q)%32, conflict-free.
// Conv tap k == A-tile row shift k: 5 accumulated K=128 GEMMs, one staging.
// B fragments straight from global (wcb, L2-hot), 16 frags (64 VGPRs) per k.
// MFMA operand-swapped: acc = mfma(W_frag, Act_frag) -> D[d][pos], so each
// lane holds 4 CONSECUTIVE d (lq*4+rr) for one position (lr) -> float4
// epilogue (vector pos/bias loads, nontemporal vector out stores).
// ---------------------------------------------------------------------------
__global__ __launch_bounds__(256, 2) void conv_main(
    const int* __restrict__ X, const ushort* __restrict__ wlt,
    const ushort* __restrict__ wcb, const float* __restrict__ bconv,
    const float* __restrict__ pos, float* __restrict__ out) {
  __shared__ __align__(16) ushort Atile[132 * 136];

  const int tid   = threadIdx.x;
  const int bm    = blockIdx.x;                 // 0..511
  const int batch = bm >> 6;
  const int nbase = (bm & 63) << 7;
  const int* Xb   = X + batch * SEQ;

  // ---- stage A: 132 rows x 16 chunks of 16B; tokens first, then gathers ----
  int  tok[9];
  bool valid[9];
#pragma unroll
  for (int it = 0; it < 9; ++it) {
    int c = tid + it * 256;
    int r = c >> 4;
    int n = nbase - 2 + r;
    bool v = (c < 2112) && (n >= 0) && (n < SEQ);
    valid[it] = v;
    tok[it] = v ? Xb[n] : 0;
  }
  uint4 val[9];
#pragma unroll
  for (int it = 0; it < 9; ++it) {
    int c = tid + it * 256;
    int ch = c & 15;
    val[it] = valid[it] ? *(const uint4*)(wlt + (size_t)tok[it] * DIM + ch * 8)
                        : make_uint4(0u, 0u, 0u, 0u);
  }
#pragma unroll
  for (int it = 0; it < 9; ++it) {
    int c = tid + it * 256;
    if (c < 2112) {
      int r = c >> 4, ch = c & 15;
      *(uint4*)&Atile[r * 136 + ch * 8] = val[it];
    }
  }
  __syncthreads();

  // ---- compute: 4 waves, each 64x64 = 4x4 frags of 16x16x32 bf16 ----
  const int wave = tid >> 6;
  const int lane = tid & 63;
  const int wm = (wave >> 1) << 6;   // position tile base (within 128)
  const int wn = (wave & 1) << 6;    // d tile base (within 128)
  const int lr = lane & 15;
  const int lq = lane >> 4;

  f32x4 acc[4][4];   // [mt = pos tile][nt = d tile]; D[d][pos] fragments
#pragma unroll
  for (int a = 0; a < 4; ++a)
#pragma unroll
    for (int b = 0; b < 4; ++b) acc[a][b] = (f32x4)0.f;

#pragma unroll
  for (int k = 0; k < 5; ++k) {
    bf16x8 B[4][4];  // [nt][kk]  W fragment: lane lr <-> d, lq <-> k-chunk
#pragma unroll
    for (int nt = 0; nt < 4; ++nt)
#pragma unroll
      for (int kk = 0; kk < 4; ++kk)
        B[nt][kk] = *(const bf16x8*)(wcb +
            ((size_t)(k * DIM + wn + nt * 16 + lr) * DIM + kk * 32 + lq * 8));
#pragma unroll
    for (int kk = 0; kk < 4; ++kk) {
      bf16x8 A[4];
#pragma unroll
      for (int mt = 0; mt < 4; ++mt)
        A[mt] = *(const bf16x8*)&Atile[(wm + mt * 16 + lr + k) * 136 + kk * 32 + lq * 8];
      // Operand-swapped: D[d][pos] = W[d][k] * Act^T[k][pos]
#pragma unroll
      for (int mt = 0; mt < 4; ++mt)
#pragma unroll
        for (int nt = 0; nt < 4; ++nt)
          acc[mt][nt] = __builtin_amdgcn_mfma_f32_16x16x32_bf16(
              B[nt][kk], A[mt], acc[mt][nt], 0, 0, 0);
    }
  }

  // ---- epilogue: lane holds d0..d0+3 (d0 = wn+nt*16+lq*4) at pos = wm+mt*16+lr
  float* outb = out + (size_t)batch * SEQ * DIM;
#pragma unroll
  for (int nt = 0; nt < 4; ++nt) {
    int d0 = wn + nt * 16 + lq * 4;
    const f32x4 bc4 = *(const f32x4*)(bconv + d0);
#pragma unroll
    for (int mt = 0; mt < 4; ++mt) {
      int gn = nbase + wm + mt * 16 + lr;
      const f32x4 p4 = *(const f32x4*)(pos + (size_t)gn * DIM + d0);
      f32x4 v = acc[mt][nt] + bc4 + p4;
      __builtin_nontemporal_store(v, (f32x4*)(outb + (size_t)gn * DIM + d0));
    }
  }
}

// ---------------------------------------------------------------------------
extern "C" void kernel_launch(void* const* d_in, const int* in_sizes, int n_in,
                              void* d_out, int out_size, void* d_ws, size_t ws_size,
                              hipStream_t stream) {
  const int*   X     = (const int*)d_in[0];
  const float* wlin  = (const float*)d_in[1];
  const float* blin  = (const float*)d_in[2];
  const float* wconv = (const float*)d_in[3];
  const float* bconv = (const float*)d_in[4];
  const float* pos   = (const float*)d_in[5];
  float*       out   = (float*)d_out;

  ushort* wcb = (ushort*)d_ws;                       // 163,840 B
  ushort* wlt = (ushort*)((char*)d_ws + 262144);     // 25.6 MB

  hipLaunchKernelGGL(build_tables, dim3(NB_WLT + 80), dim3(256), 0, stream,
                     wlin, blin, wconv, wlt, wcb);
  hipLaunchKernelGGL(conv_main, dim3(512), dim3(256), 0, stream,
                     X, wlt, wcb, bconv, pos, out);
}

// Round 3
// 142.437 us; speedup vs baseline: 1.0408x; 1.0408x over previous
//
#include <hip/hip_runtime.h>
#include <hip/hip_bf16.h>
#include <stdint.h>

#define VOCAB 100000
#define SEQ   8192
#define BATCH 8
#define DIM   128
#define NB_WLT 1563   // (VOCAB+63)/64

typedef short bf16x8 __attribute__((ext_vector_type(8)));
typedef float f32x4  __attribute__((ext_vector_type(4)));

__device__ __forceinline__ ushort f2bf(float f) {
  union { float f; uint32_t u; } v; v.f = f;
  uint32_t u = v.u;
  return (ushort)((u + 0x7FFF + ((u >> 16) & 1)) >> 16);  // RNE; inputs never NaN
}

// ---------------------------------------------------------------------------
// Fused pre-kernel: blocks [0, NB_WLT) build wlt (LDS tile transpose of W_lin
// + bias -> bf16, token-major); blocks [NB_WLT, NB_WLT+80) repack W_conv
// (d,i,k) fp32 -> wcb[k][d][i] bf16 (160 KB, L2-hot B operand).
// ---------------------------------------------------------------------------
__global__ __launch_bounds__(256) void build_tables(
    const float* __restrict__ wlin, const float* __restrict__ blin,
    const float* __restrict__ wconv, ushort* __restrict__ wlt,
    ushort* __restrict__ wcb) {
  __shared__ float tile[128 * 65];
  const int tid = threadIdx.x;

  if (blockIdx.x >= NB_WLT) {
    int e = (blockIdx.x - NB_WLT) * 1024 + tid;
#pragma unroll
    for (int i = 0; i < 4; ++i, e += 256) {
      if (e < 5 * DIM * DIM) {
        int k = e >> 14;            // / (DIM*DIM)
        int rem = e & 16383;        // % (DIM*DIM)
        int d = rem >> 7, ii = rem & 127;
        wcb[e] = f2bf(wconv[(d * DIM + ii) * 5 + k]);
      }
    }
    return;
  }

  const int t0 = blockIdx.x * 64;

  // Phase A: 8 passes, each covers 16 rows x 64 cols in float4s.
  const int c4 = (tid & 15) * 4;          // column offset within tile (0..60)
  const int rbase = tid >> 4;             // 0..15
  const bool cvalid = (t0 + c4) < VOCAB;  // VOCAB%4==0 -> whole float4 in/out
#pragma unroll
  for (int p = 0; p < 8; ++p) {
    int r = p * 16 + rbase;               // dim row 0..127
    float4 v = make_float4(0.f, 0.f, 0.f, 0.f);
    if (cvalid) v = *(const float4*)(wlin + (size_t)r * VOCAB + t0 + c4);
    float* dst = &tile[r * 65 + c4];
    dst[0] = v.x; dst[1] = v.y; dst[2] = v.z; dst[3] = v.w;
  }
  __syncthreads();

  // Phase B: thread = (chunk = tid&15, token = tid>>4 + p*16)
  const int chunk = tid & 15;
  float bias8[8];
#pragma unroll
  for (int j = 0; j < 8; ++j) bias8[j] = blin[chunk * 8 + j];

#pragma unroll
  for (int p = 0; p < 4; ++p) {
    int tl = (tid >> 4) + p * 16;         // token within tile 0..63
    int t  = t0 + tl;
    if (t >= VOCAB) continue;
    ushort u[8];
#pragma unroll
    for (int j = 0; j < 8; ++j) {
      float f = tile[(chunk * 8 + j) * 65 + tl] + bias8[j];
      u[j] = f2bf(f);
    }
    *(uint4*)(wlt + (size_t)t * DIM + chunk * 8) = *(const uint4*)u;
  }
}

// ---------------------------------------------------------------------------
// Main (restructured for occupancy): per block 64 positions x 128 d.
// Grid = 1024 blocks -> 4 blocks/CU (was 2) -> 16 waves/CU = 4 waves/SIMD.
// LDS A-tile: 68 emb rows (halo +-2) x 128 bf16, pitch 136 ushorts (272 B)
//   -> ds_read_b128 bank-balanced (68 dwords/row, (17r+q)%32 spread).
// 4 waves partition d: wave w covers 64 pos (mt=0..3) x 32 d (nt=0..1).
// Per k: only 8 B-frags live (32 VGPR) -> fits 4 waves/SIMD register budget.
// Block B-traffic = one 160 KB pass of wcb (L2-hot); total unchanged vs old.
// MFMA operand-swapped: acc = mfma(W_frag, Act_frag) -> D[d][pos]; lane holds
// 4 consecutive d -> float4 epilogue with nontemporal stores.
// ---------------------------------------------------------------------------
__global__ __launch_bounds__(256, 4) void conv_main(
    const int* __restrict__ X, const ushort* __restrict__ wlt,
    const ushort* __restrict__ wcb, const float* __restrict__ bconv,
    const float* __restrict__ pos, float* __restrict__ out) {
  __shared__ __align__(16) ushort Atile[68 * 136];

  const int tid   = threadIdx.x;
  const int bm    = blockIdx.x;                 // 0..1023
  const int batch = bm >> 7;
  const int nbase = (bm & 127) << 6;
  const int* Xb   = X + batch * SEQ;

  // ---- stage A: 68 rows x 16 chunks of 16B; tokens first, then gathers ----
  int  tok[5];
  bool valid[5];
#pragma unroll
  for (int it = 0; it < 5; ++it) {
    int c = tid + it * 256;
    int r = c >> 4;
    int n = nbase - 2 + r;
    bool v = (c < 1088) && (n >= 0) && (n < SEQ);
    valid[it] = v;
    tok[it] = v ? Xb[n] : 0;
  }
  uint4 val[5];
#pragma unroll
  for (int it = 0; it < 5; ++it) {
    int c = tid + it * 256;
    int ch = c & 15;
    val[it] = valid[it] ? *(const uint4*)(wlt + (size_t)tok[it] * DIM + ch * 8)
                        : make_uint4(0u, 0u, 0u, 0u);
  }
#pragma unroll
  for (int it = 0; it < 5; ++it) {
    int c = tid + it * 256;
    if (c < 1088) {
      int r = c >> 4, ch = c & 15;
      *(uint4*)&Atile[r * 136 + ch * 8] = val[it];
    }
  }
  __syncthreads();

  // ---- compute: 4 waves, each 64 pos x 32 d = 4x2 frags of 16x16x32 ----
  const int wave = tid >> 6;
  const int lane = tid & 63;
  const int wn = wave << 5;          // d tile base (0,32,64,96)
  const int lr = lane & 15;
  const int lq = lane >> 4;

  f32x4 acc[4][2];   // [mt = pos tile][nt = d tile]; D[d][pos] fragments
#pragma unroll
  for (int a = 0; a < 4; ++a)
#pragma unroll
    for (int b = 0; b < 2; ++b) acc[a][b] = (f32x4)0.f;

#pragma unroll
  for (int k = 0; k < 5; ++k) {
    bf16x8 B[2][4];  // [nt][kk]  W fragment: lane lr <-> d, lq <-> k-chunk
#pragma unroll
    for (int nt = 0; nt < 2; ++nt)
#pragma unroll
      for (int kk = 0; kk < 4; ++kk)
        B[nt][kk] = *(const bf16x8*)(wcb +
            ((size_t)(k * DIM + wn + nt * 16 + lr) * DIM + kk * 32 + lq * 8));
#pragma unroll
    for (int kk = 0; kk < 4; ++kk) {
      bf16x8 A[4];
#pragma unroll
      for (int mt = 0; mt < 4; ++mt)
        A[mt] = *(const bf16x8*)&Atile[(mt * 16 + lr + k) * 136 + kk * 32 + lq * 8];
      // Operand-swapped: D[d][pos] = W[d][k] * Act^T[k][pos]
#pragma unroll
      for (int mt = 0; mt < 4; ++mt)
#pragma unroll
        for (int nt = 0; nt < 2; ++nt)
          acc[mt][nt] = __builtin_amdgcn_mfma_f32_16x16x32_bf16(
              B[nt][kk], A[mt], acc[mt][nt], 0, 0, 0);
    }
  }

  // ---- epilogue: lane holds d0..d0+3 (d0 = wn+nt*16+lq*4) at pos = mt*16+lr
  float* outb = out + (size_t)batch * SEQ * DIM;
#pragma unroll
  for (int nt = 0; nt < 2; ++nt) {
    int d0 = wn + nt * 16 + lq * 4;
    const f32x4 bc4 = *(const f32x4*)(bconv + d0);
#pragma unroll
    for (int mt = 0; mt < 4; ++mt) {
      int gn = nbase + mt * 16 + lr;
      const f32x4 p4 = *(const f32x4*)(pos + (size_t)gn * DIM + d0);
      f32x4 v = acc[mt][nt] + bc4 + p4;
      __builtin_nontemporal_store(v, (f32x4*)(outb + (size_t)gn * DIM + d0));
    }
  }
}

// ---------------------------------------------------------------------------
extern "C" void kernel_launch(void* const* d_in, const int* in_sizes, int n_in,
                              void* d_out, int out_size, void* d_ws, size_t ws_size,
                              hipStream_t stream) {
  const int*   X     = (const int*)d_in[0];
  const float* wlin  = (const float*)d_in[1];
  const float* blin  = (const float*)d_in[2];
  const float* wconv = (const float*)d_in[3];
  const float* bconv = (const float*)d_in[4];
  const float* pos   = (const float*)d_in[5];
  float*       out   = (float*)d_out;

  ushort* wcb = (ushort*)d_ws;                       // 163,840 B
  ushort* wlt = (ushort*)((char*)d_ws + 262144);     // 25.6 MB

  hipLaunchKernelGGL(build_tables, dim3(NB_WLT + 80), dim3(256), 0, stream,
                     wlin, blin, wconv, wlt, wcb);
  hipLaunchKernelGGL(conv_main, dim3(1024), dim3(256), 0, stream,
                     X, wlt, wcb, bconv, pos, out);
}

// Round 4
// 140.191 us; speedup vs baseline: 1.0574x; 1.0160x over previous
//
#include <hip/hip_runtime.h>
#include <hip/hip_bf16.h>
#include <stdint.h>

#define VOCAB 100000
#define SEQ   8192
#define BATCH 8
#define DIM   128
#define NB_WLT 1563   // (VOCAB+63)/64

typedef short bf16x8 __attribute__((ext_vector_type(8)));
typedef float f32x4  __attribute__((ext_vector_type(4)));

__device__ __forceinline__ ushort f2bf(float f) {
  union { float f; uint32_t u; } v; v.f = f;
  uint32_t u = v.u;
  return (ushort)((u + 0x7FFF + ((u >> 16) & 1)) >> 16);  // RNE; inputs never NaN
}

// ---------------------------------------------------------------------------
// Fused pre-kernel: blocks [0, NB_WLT) build wlt (LDS tile transpose of W_lin
// + bias -> bf16, token-major); blocks [NB_WLT, NB_WLT+80) repack W_conv
// (d,i,k) fp32 -> wcb[k][d][i] bf16 (160 KB, L2-hot B operand).
// ---------------------------------------------------------------------------
__global__ __launch_bounds__(256) void build_tables(
    const float* __restrict__ wlin, const float* __restrict__ blin,
    const float* __restrict__ wconv, ushort* __restrict__ wlt,
    ushort* __restrict__ wcb) {
  __shared__ float tile[128 * 65];
  const int tid = threadIdx.x;

  if (blockIdx.x >= NB_WLT) {
    int e = (blockIdx.x - NB_WLT) * 1024 + tid;
#pragma unroll
    for (int i = 0; i < 4; ++i, e += 256) {
      if (e < 5 * DIM * DIM) {
        int k = e >> 14;            // / (DIM*DIM)
        int rem = e & 16383;        // % (DIM*DIM)
        int d = rem >> 7, ii = rem & 127;
        wcb[e] = f2bf(wconv[(d * DIM + ii) * 5 + k]);
      }
    }
    return;
  }

  const int t0 = blockIdx.x * 64;

  // Phase A: 8 passes, each covers 16 rows x 64 cols in float4s.
  const int c4 = (tid & 15) * 4;          // column offset within tile (0..60)
  const int rbase = tid >> 4;             // 0..15
  const bool cvalid = (t0 + c4) < VOCAB;  // VOCAB%4==0 -> whole float4 in/out
#pragma unroll
  for (int p = 0; p < 8; ++p) {
    int r = p * 16 + rbase;               // dim row 0..127
    float4 v = make_float4(0.f, 0.f, 0.f, 0.f);
    if (cvalid) v = *(const float4*)(wlin + (size_t)r * VOCAB + t0 + c4);
    float* dst = &tile[r * 65 + c4];
    dst[0] = v.x; dst[1] = v.y; dst[2] = v.z; dst[3] = v.w;
  }
  __syncthreads();

  // Phase B: thread = (chunk = tid&15, token = tid>>4 + p*16)
  const int chunk = tid & 15;
  float bias8[8];
#pragma unroll
  for (int j = 0; j < 8; ++j) bias8[j] = blin[chunk * 8 + j];

#pragma unroll
  for (int p = 0; p < 4; ++p) {
    int tl = (tid >> 4) + p * 16;         // token within tile 0..63
    int t  = t0 + tl;
    if (t >= VOCAB) continue;
    ushort u[8];
#pragma unroll
    for (int j = 0; j < 8; ++j) {
      float f = tile[(chunk * 8 + j) * 65 + tl] + bias8[j];
      u[j] = f2bf(f);
    }
    *(uint4*)(wlt + (size_t)t * DIM + chunk * 8) = *(const uint4*)u;
  }
}

// ---------------------------------------------------------------------------
// Main: per block 64 positions x 128 d.  Grid = 1024 -> 4 blocks/CU.
// LDS A-tile: 68 emb rows (halo +-2) x 128 bf16, pitch 136 ushorts (272 B).
// 4 waves partition d: wave w covers 64 pos (mt=0..3) x 32 d (nt=0..1).
// MFMA operand-swapped: acc = mfma(W_frag, Act_frag) -> D[d][pos]; lane holds
// 4 consecutive d -> float4 epilogue. Stores are NORMAL cached f32x4 stores:
// L2 write-back merges the 64-B lane segments into full 128-B lines
// (nontemporal bypass caused ~7 MB write amplification: 40 vs 33.5 MB ideal).
// ---------------------------------------------------------------------------
__global__ __launch_bounds__(256, 4) void conv_main(
    const int* __restrict__ X, const ushort* __restrict__ wlt,
    const ushort* __restrict__ wcb, const float* __restrict__ bconv,
    const float* __restrict__ pos, float* __restrict__ out) {
  __shared__ __align__(16) ushort Atile[68 * 136];

  const int tid   = threadIdx.x;
  const int bm    = blockIdx.x;                 // 0..1023
  const int batch = bm >> 7;
  const int nbase = (bm & 127) << 6;
  const int* Xb   = X + batch * SEQ;

  // ---- stage A: 68 rows x 16 chunks of 16B; tokens first, then gathers ----
  int  tok[5];
  bool valid[5];
#pragma unroll
  for (int it = 0; it < 5; ++it) {
    int c = tid + it * 256;
    int r = c >> 4;
    int n = nbase - 2 + r;
    bool v = (c < 1088) && (n >= 0) && (n < SEQ);
    valid[it] = v;
    tok[it] = v ? Xb[n] : 0;
  }
  uint4 val[5];
#pragma unroll
  for (int it = 0; it < 5; ++it) {
    int c = tid + it * 256;
    int ch = c & 15;
    val[it] = valid[it] ? *(const uint4*)(wlt + (size_t)tok[it] * DIM + ch * 8)
                        : make_uint4(0u, 0u, 0u, 0u);
  }
#pragma unroll
  for (int it = 0; it < 5; ++it) {
    int c = tid + it * 256;
    if (c < 1088) {
      int r = c >> 4, ch = c & 15;
      *(uint4*)&Atile[r * 136 + ch * 8] = val[it];
    }
  }
  __syncthreads();

  // ---- compute: 4 waves, each 64 pos x 32 d = 4x2 frags of 16x16x32 ----
  const int wave = tid >> 6;
  const int lane = tid & 63;
  const int wn = wave << 5;          // d tile base (0,32,64,96)
  const int lr = lane & 15;
  const int lq = lane >> 4;

  f32x4 acc[4][2];   // [mt = pos tile][nt = d tile]; D[d][pos] fragments
#pragma unroll
  for (int a = 0; a < 4; ++a)
#pragma unroll
    for (int b = 0; b < 2; ++b) acc[a][b] = (f32x4)0.f;

#pragma unroll
  for (int k = 0; k < 5; ++k) {
    bf16x8 B[2][4];  // [nt][kk]  W fragment: lane lr <-> d, lq <-> k-chunk
#pragma unroll
    for (int nt = 0; nt < 2; ++nt)
#pragma unroll
      for (int kk = 0; kk < 4; ++kk)
        B[nt][kk] = *(const bf16x8*)(wcb +
            ((size_t)(k * DIM + wn + nt * 16 + lr) * DIM + kk * 32 + lq * 8));
#pragma unroll
    for (int kk = 0; kk < 4; ++kk) {
      bf16x8 A[4];
#pragma unroll
      for (int mt = 0; mt < 4; ++mt)
        A[mt] = *(const bf16x8*)&Atile[(mt * 16 + lr + k) * 136 + kk * 32 + lq * 8];
      // Operand-swapped: D[d][pos] = W[d][k] * Act^T[k][pos]
#pragma unroll
      for (int mt = 0; mt < 4; ++mt)
#pragma unroll
        for (int nt = 0; nt < 2; ++nt)
          acc[mt][nt] = __builtin_amdgcn_mfma_f32_16x16x32_bf16(
              B[nt][kk], A[mt], acc[mt][nt], 0, 0, 0);
    }
  }

  // ---- epilogue: lane holds d0..d0+3 (d0 = wn+nt*16+lq*4) at pos = mt*16+lr
  float* outb = out + (size_t)batch * SEQ * DIM;
#pragma unroll
  for (int nt = 0; nt < 2; ++nt) {
    int d0 = wn + nt * 16 + lq * 4;
    const f32x4 bc4 = *(const f32x4*)(bconv + d0);
#pragma unroll
    for (int mt = 0; mt < 4; ++mt) {
      int gn = nbase + mt * 16 + lr;
      const f32x4 p4 = *(const f32x4*)(pos + (size_t)gn * DIM + d0);
      f32x4 v = acc[mt][nt] + bc4 + p4;
      *(f32x4*)(outb + (size_t)gn * DIM + d0) = v;
    }
  }
}

// ---------------------------------------------------------------------------
extern "C" void kernel_launch(void* const* d_in, const int* in_sizes, int n_in,
                              void* d_out, int out_size, void* d_ws, size_t ws_size,
                              hipStream_t stream) {
  const int*   X     = (const int*)d_in[0];
  const float* wlin  = (const float*)d_in[1];
  const float* blin  = (const float*)d_in[2];
  const float* wconv = (const float*)d_in[3];
  const float* bconv = (const float*)d_in[4];
  const float* pos   = (const float*)d_in[5];
  float*       out   = (float*)d_out;

  ushort* wcb = (ushort*)d_ws;                       // 163,840 B
  ushort* wlt = (ushort*)((char*)d_ws + 262144);     // 25.6 MB

  hipLaunchKernelGGL(build_tables, dim3(NB_WLT + 80), dim3(256), 0, stream,
                     wlin, blin, wconv, wlt, wcb);
  hipLaunchKernelGGL(conv_main, dim3(1024), dim3(256), 0, stream,
                     X, wlt, wcb, bconv, pos, out);
}